// Round 1
// baseline (206.538 us; speedup 1.0000x reference)
//
#include <hip/hip_runtime.h>

typedef unsigned short u16;
typedef unsigned int u32;
typedef __attribute__((ext_vector_type(8))) short short8;
typedef __attribute__((ext_vector_type(4))) float f32x4;

#define DD 2048
constexpr int OFF_P2   = 512000;            // 250*2048
constexpr int OFF_CTX1 = 518750;            // +250*27
constexpr int OFF_P1   = 574046;            // +27*2048

__device__ __forceinline__ u16 f2bf(float f){
  u32 u = __float_as_uint(f);
  u += 0x7fffu + ((u >> 16) & 1u);
  return (u16)(u >> 16);
}
__device__ __forceinline__ float bf2f(u32 us){
  return __uint_as_float(us << 16);
}
__device__ __forceinline__ u32 pk(float a, float b){
  return (u32)f2bf(a) | ((u32)f2bf(b) << 16);
}

// ---------------------------------------------------------------------------
// L1: NT GEMMs.  blocks 0..127: v1 = in1 @ Wv1^T + bv1  -> d_out (ctx2 slot)
//     blocks 128..223: q2/k2/v2 = in2 @ {Wq2,Wk2,Wv2}^T + bias
//       q2,k2 -> bf16 ws ; v2 -> fp32 into d_out ctx1 slot (scaled later)
// ---------------------------------------------------------------------------
__global__ __launch_bounds__(256) void k_gemm_nt(
    const float* __restrict__ in1, const float* __restrict__ in2,
    const float* __restrict__ Wv1, const float* __restrict__ bv1,
    const float* __restrict__ Wq2, const float* __restrict__ bq2,
    const float* __restrict__ Wk2, const float* __restrict__ bk2,
    const float* __restrict__ Wv2, const float* __restrict__ bv2,
    float* __restrict__ outv1, u16* __restrict__ q2b, u16* __restrict__ k2b,
    float* __restrict__ v2f)
{
  __shared__ u16 lds_a[64*72];
  __shared__ u16 lds_b[64*72];
  const int b = blockIdx.x, t = threadIdx.x;
  const float *A, *B, *bias;
  int Mreal, m0, n0, kind;
  if (b < 128){
    A = in1; Mreal = 250; m0 = (b>>5)*64; n0 = (b&31)*64; B = Wv1; bias = bv1; kind = 0;
  } else {
    int s = b - 128, mat = s>>5;
    n0 = (s&31)*64; A = in2; Mreal = 27; m0 = 0;
    B    = (mat==0) ? Wq2 : ((mat==1) ? Wk2 : Wv2);
    bias = (mat==0) ? bq2 : ((mat==1) ? bk2 : bv2);
    kind = 1 + mat;
  }
  const int w = t>>6, l = t&63, wm = w>>1, wn = w&1;
  const int srow = t>>4, scol = (t&15)*4;
  float4 pfa[4], pfb[4];

  auto loadt = [&](int k0){
#pragma unroll
    for (int p=0;p<4;p++){
      int row = p*16 + srow;
      int gm = m0 + row;
      if (gm < Mreal) pfa[p] = *(const float4*)&A[(size_t)gm*DD + k0 + scol];
      else { pfa[p].x=0.f; pfa[p].y=0.f; pfa[p].z=0.f; pfa[p].w=0.f; }
      pfb[p] = *(const float4*)&B[(size_t)(n0+row)*DD + k0 + scol];
    }
  };

  f32x4 acc[2][2];
#pragma unroll
  for (int i=0;i<2;i++)
#pragma unroll
    for (int j=0;j<2;j++) acc[i][j] = (f32x4){0.f,0.f,0.f,0.f};

  loadt(0);
#pragma unroll 1
  for (int kt=0; kt<32; ++kt){
    __syncthreads();
#pragma unroll
    for (int p=0;p<4;p++){
      int row = p*16 + srow;
      uint2 av; av.x = pk(pfa[p].x, pfa[p].y); av.y = pk(pfa[p].z, pfa[p].w);
      *(uint2*)&lds_a[row*72 + scol] = av;
      uint2 bw; bw.x = pk(pfb[p].x, pfb[p].y); bw.y = pk(pfb[p].z, pfb[p].w);
      *(uint2*)&lds_b[row*72 + scol] = bw;
    }
    __syncthreads();
    if (kt < 31) loadt((kt+1)*64);
#pragma unroll
    for (int kk=0; kk<2; ++kk){
      const int kf = kk*32 + (l>>4)*8;
      short8 af[2], bfr[2];
#pragma unroll
      for (int mf=0;mf<2;mf++) af[mf]  = *(const short8*)&lds_a[(wm*32+mf*16+(l&15))*72 + kf];
#pragma unroll
      for (int nf=0;nf<2;nf++) bfr[nf] = *(const short8*)&lds_b[(wn*32+nf*16+(l&15))*72 + kf];
#pragma unroll
      for (int mf=0;mf<2;mf++)
#pragma unroll
        for (int nf=0;nf<2;nf++)
          acc[mf][nf] = __builtin_amdgcn_mfma_f32_16x16x32_bf16(af[mf], bfr[nf], acc[mf][nf], 0, 0, 0);
    }
  }
#pragma unroll
  for (int mf=0;mf<2;mf++)
#pragma unroll
    for (int nf=0;nf<2;nf++){
      int colg = n0 + wn*32 + nf*16 + (l&15);
      float bv = bias[colg];
#pragma unroll
      for (int r=0;r<4;r++){
        int m = m0 + wm*32 + mf*16 + ((l>>4)<<2) + r;
        if (m < Mreal){
          float v = acc[mf][nf][r] + bv;
          size_t off = (size_t)m*DD + colg;
          if (kind == 0)      outv1[off] = v;
          else if (kind == 1) q2b[off] = f2bf(v);
          else if (kind == 2) k2b[off] = f2bf(v);
          else                v2f[off] = v;
        }
      }
    }
}

// ---------------------------------------------------------------------------
// L2: NN GEMMs with K-split + atomic accumulate.
//   t1 = q2 @ Wk1 -> t1f (fp32, zero-initialized) ; t2 = k2 @ Wq1 -> t2f
// ---------------------------------------------------------------------------
__global__ __launch_bounds__(256) void k_gemm_nn(
    const u16* __restrict__ q2b, const u16* __restrict__ k2b,
    const float* __restrict__ Wk1, const float* __restrict__ Wq1,
    float* __restrict__ t1f, float* __restrict__ t2f)
{
  __shared__ u16 lds_a[32*72];
  __shared__ u16 lds_b[64*36];
  const int b = blockIdx.x, t = threadIdx.x;
  const int mat = b>>7, rem = b&127, nt = rem>>1, ks = rem&1;
  const int n0 = nt*32, kbase = ks*1024;
  const u16* A = mat ? k2b : q2b;
  const float* B = mat ? Wq1 : Wk1;
  float* OUT = mat ? t2f : t1f;
  const int w = t>>6, l = t&63, mf = w>>1, nf = w&1;
  const int arow = t>>3, acol8 = (t&7)*8;
  uint4 pa; float4 pb[2];
  auto loadt = [&](int k0){
    if (arow < 27) pa = *(const uint4*)&A[(size_t)arow*DD + k0 + acol8];
    else { pa.x=0u; pa.y=0u; pa.z=0u; pa.w=0u; }
#pragma unroll
    for (int p=0;p<2;p++){
      int idx = p*256 + t, rk = idx>>3, c4 = (idx&7)*4;
      pb[p] = *(const float4*)&B[(size_t)(k0+rk)*DD + n0 + c4];
    }
  };
  f32x4 acc = (f32x4){0.f,0.f,0.f,0.f};
  loadt(kbase);
#pragma unroll 1
  for (int kt=0; kt<16; ++kt){
    __syncthreads();
    *(uint4*)&lds_a[arow*72 + acol8] = pa;
#pragma unroll
    for (int p=0;p<2;p++){
      int idx = p*256 + t, rk = idx>>3, c4 = (idx&7)*4;
      uint2 bv; bv.x = pk(pb[p].x, pb[p].y); bv.y = pk(pb[p].z, pb[p].w);
      *(uint2*)&lds_b[rk*36 + c4] = bv;
    }
    __syncthreads();
    if (kt < 15) loadt(kbase + (kt+1)*64);
#pragma unroll
    for (int kk=0; kk<2; ++kk){
      const int kf = kk*32 + (l>>4)*8;
      short8 af = *(const short8*)&lds_a[(mf*16+(l&15))*72 + kf];
      short8 bfr;
      const int n = nf*16 + (l&15);
#pragma unroll
      for (int j=0;j<8;j++) bfr[j] = (short)lds_b[(kf+j)*36 + n];
      acc = __builtin_amdgcn_mfma_f32_16x16x32_bf16(af, bfr, acc, 0, 0, 0);
    }
  }
  const int col = n0 + nf*16 + (l&15);
#pragma unroll
  for (int r=0;r<4;r++){
    int row = mf*16 + ((l>>4)<<2) + r;
    atomicAdd(&OUT[(size_t)row*DD + col], acc[r]);
  }
}

// ---------------------------------------------------------------------------
// L3a: S1 = t1 @ in1^T, S2 = t2 @ in1^T  (K-split atomic MFMA, S [32 x 256])
//      + bias dot blocks: c1[t] = q2[t].bk1 ; r2[t] = k2[t].bq1
// ---------------------------------------------------------------------------
__global__ __launch_bounds__(256) void k_sgemm(
    const float* __restrict__ t1f, const float* __restrict__ t2f,
    const float* __restrict__ in1,
    const u16* __restrict__ q2b, const u16* __restrict__ k2b,
    const float* __restrict__ bk1, const float* __restrict__ bq1,
    float* __restrict__ S1f, float* __restrict__ S2f,
    float* __restrict__ c1acc, float* __restrict__ r2acc)
{
  __shared__ u16 lds_a[32*72];
  __shared__ u16 lds_b[64*72];
  const int b = blockIdx.x, t = threadIdx.x;
  const int w = t>>6, l = t&63;
  if (b < 256){
    const int mat = b>>7, rem = b&127, jt = rem>>5, ks = rem&31;
    const int j0 = jt*64, kbase = ks*64;
    const float* Af = mat ? t2f : t1f;
    float* OUT = mat ? S2f : S1f;
#pragma unroll
    for (int p=0;p<2;p++){
      int f4i = p*256 + t, row = f4i>>4, c4 = (f4i&15)*4;
      float4 v = *(const float4*)&Af[(size_t)row*DD + kbase + c4];
      uint2 pv; pv.x = pk(v.x, v.y); pv.y = pk(v.z, v.w);
      *(uint2*)&lds_a[row*72 + c4] = pv;
    }
#pragma unroll
    for (int p=0;p<4;p++){
      int f4i = p*256 + t, row = f4i>>4, c4 = (f4i&15)*4;
      int j = j0 + row;
      float4 v;
      if (j < 250) v = *(const float4*)&in1[(size_t)j*DD + kbase + c4];
      else { v.x=0.f; v.y=0.f; v.z=0.f; v.w=0.f; }
      uint2 pv; pv.x = pk(v.x, v.y); pv.y = pk(v.z, v.w);
      *(uint2*)&lds_b[row*72 + c4] = pv;
    }
    __syncthreads();
    const int wm = w>>1, wn = w&1;
    f32x4 acc[2];
    acc[0] = (f32x4){0.f,0.f,0.f,0.f};
    acc[1] = (f32x4){0.f,0.f,0.f,0.f};
#pragma unroll
    for (int kk=0; kk<2; ++kk){
      const int kf = kk*32 + (l>>4)*8;
      short8 af = *(const short8*)&lds_a[(wm*16+(l&15))*72 + kf];
#pragma unroll
      for (int nf=0;nf<2;nf++){
        short8 bfr = *(const short8*)&lds_b[(wn*32+nf*16+(l&15))*72 + kf];
        acc[nf] = __builtin_amdgcn_mfma_f32_16x16x32_bf16(af, bfr, acc[nf], 0, 0, 0);
      }
    }
#pragma unroll
    for (int nf=0;nf<2;nf++){
      int col = j0 + wn*32 + nf*16 + (l&15);
#pragma unroll
      for (int r=0;r<4;r++){
        int row = wm*16 + ((l>>4)<<2) + r;
        atomicAdd(&OUT[row*256 + col], acc[nf][r]);
      }
    }
  } else {
    const int s = b - 256, mat = s>>3, kc = s&7, kbase = kc*256;
    const u16* Ab = mat ? k2b : q2b;
    const float* bias = mat ? bq1 : bk1;
    float* OUT = mat ? r2acc : c1acc;
    for (int tt = w; tt < 27; tt += 4){
      int e = kbase + l*4;
      uint2 aa = *(const uint2*)&Ab[(size_t)tt*DD + e];
      float4 bb = *(const float4*)&bias[e];
      float sum = bf2f(aa.x & 0xffffu)*bb.x + bf2f(aa.x >> 16)*bb.y
                + bf2f(aa.y & 0xffffu)*bb.z + bf2f(aa.y >> 16)*bb.w;
#pragma unroll
      for (int off=32; off; off>>=1) sum += __shfl_xor(sum, off);
      if (l == 0) atomicAdd(&OUT[tt], sum);
    }
  }
}

// ---------------------------------------------------------------------------
// L3b: sigmoid + probs writes + g1 (atomic) + g2 + in-place ctx2 scaling
// ---------------------------------------------------------------------------
__global__ __launch_bounds__(256) void k_finish(
    const float* __restrict__ S1f, const float* __restrict__ S2f,
    const float* __restrict__ c1acc, const float* __restrict__ r2acc,
    const float* __restrict__ w_fc1, const float* __restrict__ w_fc2,
    const float* __restrict__ b_fc1p, const float* __restrict__ b_fc2p,
    float* __restrict__ g1acc, float* __restrict__ d_out)
{
  const int b = blockIdx.x, t = threadIdx.x, w = t>>6, l = t&63;
  const int j = b*4 + w;
  if (j >= 250) return;
  const float scale = 0.022097086912079608f;   // 1/sqrt(2048)
  if (l < 27){
    float s1 = (S1f[l*256 + j] + c1acc[l]) * scale;
    float p1 = 1.f / (1.f + expf(-s1));
    d_out[OFF_P1 + l*250 + j] = p1;
    atomicAdd(&g1acc[l], p1 * w_fc1[j]);
  }
  float gv = 0.f;
  if (l < 27){
    float s2 = (S2f[l*256 + j] + r2acc[l]) * scale;
    float p2 = 1.f / (1.f + expf(-s2));
    d_out[OFF_P2 + j*27 + l] = p2;
    gv = p2 * w_fc2[l];
  }
#pragma unroll
  for (int off=32; off; off>>=1) gv += __shfl_xor(gv, off);
  const float g2 = gv, bfc2 = b_fc2p[0];
#pragma unroll
  for (int i=0;i<8;i++){
    int e4 = l + 64*i;
    float4 v = *(const float4*)&d_out[(size_t)j*DD + e4*4];
    v.x = v.x*g2 + bfc2; v.y = v.y*g2 + bfc2;
    v.z = v.z*g2 + bfc2; v.w = v.w*g2 + bfc2;
    *(float4*)&d_out[(size_t)j*DD + e4*4] = v;
  }
}

// ---------------------------------------------------------------------------
// L4: ctx1 = v2 * g1[t] + b_fc1  (in-place on the ctx1 slot holding v2)
// ---------------------------------------------------------------------------
__global__ __launch_bounds__(256) void k_ctx1(
    const float* __restrict__ g1acc, const float* __restrict__ b_fc1p,
    float* __restrict__ d_out)
{
  const int i = blockIdx.x*256 + threadIdx.x;   // float2 index
  if (i >= 27*1024) return;
  const int row = i >> 10, c2 = (i & 1023)*2;
  const float g = g1acc[row], bb = b_fc1p[0];
  float* p = &d_out[OFF_CTX1 + (size_t)row*DD + c2];
  float2 v = *(const float2*)p;
  v.x = v.x*g + bb; v.y = v.y*g + bb;
  *(float2*)p = v;
}

// ---------------------------------------------------------------------------
extern "C" void kernel_launch(void* const* d_in, const int* in_sizes, int n_in,
                              void* d_out, int out_size, void* d_ws, size_t ws_size,
                              hipStream_t stream)
{
  const float* in1 = (const float*)d_in[0];
  const float* in2 = (const float*)d_in[1];
  const float* Wq1 = (const float*)d_in[2];  const float* bq1 = (const float*)d_in[3];
  const float* Wk1 = (const float*)d_in[4];  const float* bk1 = (const float*)d_in[5];
  const float* Wv1 = (const float*)d_in[6];  const float* bv1 = (const float*)d_in[7];
  const float* Wq2 = (const float*)d_in[8];  const float* bq2 = (const float*)d_in[9];
  const float* Wk2 = (const float*)d_in[10]; const float* bk2 = (const float*)d_in[11];
  const float* Wv2 = (const float*)d_in[12]; const float* bv2 = (const float*)d_in[13];
  const float* wfc1 = (const float*)d_in[14]; const float* bfc1 = (const float*)d_in[15];
  const float* wfc2 = (const float*)d_in[16]; const float* bfc2 = (const float*)d_in[17];
  float* out = (float*)d_out;

  float* ws    = (float*)d_ws;
  float* g1acc = ws;                 // 32
  float* c1acc = ws + 32;            // 32
  float* r2acc = ws + 64;            // 32
  float* S1f   = ws + 96;            // 32*256
  float* S2f   = S1f + 32*256;       // 32*256
  float* t1f   = S2f + 32*256;       // 32*2048
  float* t2f   = t1f + 32*2048;      // 32*2048
  float* zend  = t2f + 32*2048;
  u16*   q2b   = (u16*)zend;         // 32*2048 bf16
  u16*   k2b   = q2b + 32*2048;      // 32*2048 bf16
  float* v2f   = out + OFF_CTX1;     // v2 parked in ctx1 output slot

  hipMemsetAsync(d_ws, 0, (size_t)((char*)zend - (char*)d_ws), stream);
  k_gemm_nt<<<224, 256, 0, stream>>>(in1, in2, Wv1, bv1, Wq2, bq2, Wk2, bk2,
                                     Wv2, bv2, out, q2b, k2b, v2f);
  k_gemm_nn<<<256, 256, 0, stream>>>(q2b, k2b, Wk1, Wq1, t1f, t2f);
  k_sgemm<<<272, 256, 0, stream>>>(t1f, t2f, in1, q2b, k2b, bk1, bq1,
                                   S1f, S2f, c1acc, r2acc);
  k_finish<<<63, 256, 0, stream>>>(S1f, S2f, c1acc, r2acc, wfc1, wfc2,
                                   bfc1, bfc2, g1acc, out);
  k_ctx1<<<108, 256, 0, stream>>>(g1acc, bfc1, out);
}

// Round 2
// 205.817 us; speedup vs baseline: 1.0035x; 1.0035x over previous
//
#include <hip/hip_runtime.h>

typedef unsigned short u16;
typedef unsigned int u32;
typedef __attribute__((ext_vector_type(8))) short short8;
typedef __attribute__((ext_vector_type(4))) float f32x4;

#define DD 2048
constexpr int OFF_P2   = 512000;            // 250*2048
constexpr int OFF_CTX1 = 518750;            // +250*27
constexpr int OFF_P1   = 574046;            // +27*2048

// workspace layout (float offsets)
constexpr int SLB = 512000;                 // 250*2048
constexpr int SLS = 55296;                  // 27*2048
constexpr int Q1P = 0;                      // [2][SLB]
constexpr int K1P = 1024000;                // [2][SLB]
constexpr int V1P = 2048000;                // [2][SLB]
constexpr int Q2P = 3072000;                // [4][SLS]
constexpr int K2P = Q2P + 4*SLS;            // [4][SLS]
constexpr int V2P = K2P + 4*SLS;            // [4][SLS]
constexpr int S1P = V2P + 4*SLS;            // [8][32*256]
constexpr int S2P = S1P + 8*8192;           // [8][32*256]
constexpr int G1A = S2P + 8*8192;           // [32]

__device__ __forceinline__ u16 f2bf(float f){
  u32 u = __float_as_uint(f);
  u += 0x7fffu + ((u >> 16) & 1u);
  return (u16)(u >> 16);
}
__device__ __forceinline__ u32 pk(float a, float b){
  return (u32)f2bf(a) | ((u32)f2bf(b) << 16);
}

struct P6 { const float* W[6]; const float* b[6]; };

// ---------------------------------------------------------------------------
// K1: all six NT projections with K-split, fp32 partials to ws.
//   blocks 0..767:  q1/k1/v1 = in1 @ W^T (+bias on ks==0); 4 mtiles x 32 ntiles x 2 ks
//   blocks 768..1151: q2/k2/v2 = in2 @ W^T; 32 ntiles x 4 ks
// ---------------------------------------------------------------------------
__global__ __launch_bounds__(256) void k6nt(
    const float* __restrict__ in1, const float* __restrict__ in2,
    P6 par, float* __restrict__ ws)
{
  __shared__ u16 lds_a[64*72];
  __shared__ u16 lds_b[64*72];
  const int b = blockIdx.x, t = threadIdx.x;
  const float* A; int Mreal, m0, n0, kbase, KT, g; float* outp;
  if (b < 768){
    g = b >> 8; int r = b & 255;
    m0 = (r >> 6) * 64; int r2 = r & 63; n0 = (r2 >> 1) * 64; int ks = r2 & 1;
    A = in1; Mreal = 250; kbase = ks * 1024; KT = 16;
    outp = ws + g * (2*SLB) + ks * SLB;
  } else {
    int s = b - 768; g = 3 + s / 128; int r = s % 128;
    n0 = (r >> 2) * 64; int ks = r & 3;
    A = in2; Mreal = 27; m0 = 0; kbase = ks * 512; KT = 8;
    outp = ws + Q2P + (g - 3) * (4*SLS) + ks * SLS;
  }
  const bool addb = (kbase == 0);
  const float* Bw = par.W[g];
  const float* bias = par.b[g];

  const int w = t>>6, l = t&63, wm = w>>1, wn = w&1;
  const int srow = t>>4, scol = (t&15)*4;
  float4 pfa[4], pfb[4];

  auto loadt = [&](int k0){
#pragma unroll
    for (int p=0;p<4;p++){
      int row = p*16 + srow;
      int gm = m0 + row;
      if (gm < Mreal) pfa[p] = *(const float4*)&A[(size_t)gm*DD + k0 + scol];
      else { pfa[p].x=0.f; pfa[p].y=0.f; pfa[p].z=0.f; pfa[p].w=0.f; }
      pfb[p] = *(const float4*)&Bw[(size_t)(n0+row)*DD + k0 + scol];
    }
  };

  f32x4 acc[2][2];
#pragma unroll
  for (int i=0;i<2;i++)
#pragma unroll
    for (int j=0;j<2;j++) acc[i][j] = (f32x4){0.f,0.f,0.f,0.f};

  loadt(kbase);
#pragma unroll 1
  for (int kt=0; kt<KT; ++kt){
    __syncthreads();
#pragma unroll
    for (int p=0;p<4;p++){
      int row = p*16 + srow;
      uint2 av; av.x = pk(pfa[p].x, pfa[p].y); av.y = pk(pfa[p].z, pfa[p].w);
      *(uint2*)&lds_a[row*72 + scol] = av;
      uint2 bw; bw.x = pk(pfb[p].x, pfb[p].y); bw.y = pk(pfb[p].z, pfb[p].w);
      *(uint2*)&lds_b[row*72 + scol] = bw;
    }
    __syncthreads();
    if (kt < KT-1) loadt(kbase + (kt+1)*64);
#pragma unroll
    for (int kk=0; kk<2; ++kk){
      const int kf = kk*32 + (l>>4)*8;
      short8 af[2], bfr[2];
#pragma unroll
      for (int mf=0;mf<2;mf++) af[mf]  = *(const short8*)&lds_a[(wm*32+mf*16+(l&15))*72 + kf];
#pragma unroll
      for (int nf=0;nf<2;nf++) bfr[nf] = *(const short8*)&lds_b[(wn*32+nf*16+(l&15))*72 + kf];
#pragma unroll
      for (int mf=0;mf<2;mf++)
#pragma unroll
        for (int nf=0;nf<2;nf++)
          acc[mf][nf] = __builtin_amdgcn_mfma_f32_16x16x32_bf16(af[mf], bfr[nf], acc[mf][nf], 0, 0, 0);
    }
  }
#pragma unroll
  for (int mf=0;mf<2;mf++)
#pragma unroll
    for (int nf=0;nf<2;nf++){
      int colg = n0 + wn*32 + nf*16 + (l&15);
      float bv = addb ? bias[colg] : 0.f;
#pragma unroll
      for (int r=0;r<4;r++){
        int m = m0 + wm*32 + mf*16 + ((l>>4)<<2) + r;
        if (m < Mreal) outp[(size_t)m*DD + colg] = acc[mf][nf][r] + bv;
      }
    }
}

// ---------------------------------------------------------------------------
// K2: S1 = q2 @ k1^T  and  T2 (=S2^T) = k2 @ q1^T, K-split partials.
//   64 blocks: mat(2) x jtile(4 of 64 over 250) x ks(8 of 256 over K=2048)
//   operands reconstructed by summing producer partials during staging.
// ---------------------------------------------------------------------------
__global__ __launch_bounds__(256) void kS(float* __restrict__ ws)
{
  __shared__ u16 lds_a[32*72];
  __shared__ u16 lds_b[64*72];
  const int b = blockIdx.x, t = threadIdx.x;
  const int mat = b>>5, r = b&31, jt = r>>3, ks = r&7;
  const int j0 = jt*64, kbase = ks*256;
  const float* Ap = ws + (mat ? K2P : Q2P);   // [4][27x2048]
  const float* Bp = ws + (mat ? Q1P : K1P);   // [2][250x2048]
  float* OUT = ws + (mat ? S2P : S1P) + ks*8192;
  const int w = t>>6, l = t&63, wm = w>>1, wn = w&1;
  f32x4 acc[2];
  acc[0] = (f32x4){0.f,0.f,0.f,0.f};
  acc[1] = (f32x4){0.f,0.f,0.f,0.f};
#pragma unroll 1
  for (int kt=0; kt<4; ++kt){
    const int kc = kbase + kt*64;
    __syncthreads();
#pragma unroll
    for (int p=0;p<2;p++){
      int f4i = p*256 + t, row = f4i>>4, c4 = (f4i&15)*4;
      float4 v; v.x=0.f; v.y=0.f; v.z=0.f; v.w=0.f;
      if (row < 27){
        const float* base = Ap + (size_t)row*DD + kc + c4;
        float4 v0 = *(const float4*)(base);
        float4 v1 = *(const float4*)(base + SLS);
        float4 v2 = *(const float4*)(base + 2*SLS);
        float4 v3 = *(const float4*)(base + 3*SLS);
        v.x = (v0.x+v1.x)+(v2.x+v3.x); v.y = (v0.y+v1.y)+(v2.y+v3.y);
        v.z = (v0.z+v1.z)+(v2.z+v3.z); v.w = (v0.w+v1.w)+(v2.w+v3.w);
      }
      uint2 pv; pv.x = pk(v.x, v.y); pv.y = pk(v.z, v.w);
      *(uint2*)&lds_a[row*72 + c4] = pv;
    }
#pragma unroll
    for (int p=0;p<4;p++){
      int f4i = p*256 + t, row = f4i>>4, c4 = (f4i&15)*4;
      int j = j0 + row;
      float4 v; v.x=0.f; v.y=0.f; v.z=0.f; v.w=0.f;
      if (j < 250){
        const float* base = Bp + (size_t)j*DD + kc + c4;
        float4 v0 = *(const float4*)(base);
        float4 v1 = *(const float4*)(base + SLB);
        v.x = v0.x+v1.x; v.y = v0.y+v1.y; v.z = v0.z+v1.z; v.w = v0.w+v1.w;
      }
      uint2 pv; pv.x = pk(v.x, v.y); pv.y = pk(v.z, v.w);
      *(uint2*)&lds_b[row*72 + c4] = pv;
    }
    __syncthreads();
#pragma unroll
    for (int kk=0; kk<2; ++kk){
      const int kf = kk*32 + (l>>4)*8;
      short8 af = *(const short8*)&lds_a[(wm*16+(l&15))*72 + kf];
#pragma unroll
      for (int nf=0;nf<2;nf++){
        short8 bfr = *(const short8*)&lds_b[(wn*32+nf*16+(l&15))*72 + kf];
        acc[nf] = __builtin_amdgcn_mfma_f32_16x16x32_bf16(af, bfr, acc[nf], 0, 0, 0);
      }
    }
  }
#pragma unroll
  for (int nf=0;nf<2;nf++){
    int col = j0 + wn*32 + nf*16 + (l&15);
#pragma unroll
    for (int rr=0;rr<4;rr++){
      int row = wm*16 + ((l>>4)<<2) + rr;
      OUT[row*256 + col] = acc[nf][rr];
    }
  }
}

// ---------------------------------------------------------------------------
// K3: sum S partials -> sigmoid -> probs1/probs2 writes, g1 atomics, g2
//     reduce, ctx2 = (v1p0+v1p1)*g2 + b_fc2 written to d_out.
// ---------------------------------------------------------------------------
__global__ __launch_bounds__(256) void k_finish(
    const float* __restrict__ ws,
    const float* __restrict__ w_fc1, const float* __restrict__ w_fc2,
    const float* __restrict__ b_fc1p, const float* __restrict__ b_fc2p,
    float* __restrict__ g1acc, float* __restrict__ d_out)
{
  const int b = blockIdx.x, t = threadIdx.x, w = t>>6, l = t&63;
  const int j = b*4 + w;
  if (j >= 250) return;
  const float scale = 0.022097086912079608f;   // 1/sqrt(2048)
  float gv = 0.f;
  if (l < 27){
    const float* S1p = ws + S1P;
    const float* S2p = ws + S2P;
    float s1 = 0.f, s2 = 0.f;
#pragma unroll
    for (int p=0;p<8;p++){
      s1 += S1p[p*8192 + l*256 + j];
      s2 += S2p[p*8192 + l*256 + j];
    }
    float p1 = 1.f / (1.f + expf(-s1*scale));
    float p2 = 1.f / (1.f + expf(-s2*scale));
    d_out[OFF_P1 + l*250 + j] = p1;
    d_out[OFF_P2 + j*27 + l] = p2;
    atomicAdd(&g1acc[l], p1 * w_fc1[j]);
    gv = p2 * w_fc2[l];
  }
#pragma unroll
  for (int off=32; off; off>>=1) gv += __shfl_xor(gv, off);
  const float g2 = gv, bfc2 = b_fc2p[0];
  const float* v1a = ws + V1P;
  const float* v1b = ws + V1P + SLB;
#pragma unroll
  for (int i=0;i<8;i++){
    int e4 = (l + 64*i)*4;
    float4 va = *(const float4*)&v1a[(size_t)j*DD + e4];
    float4 vb = *(const float4*)&v1b[(size_t)j*DD + e4];
    float4 o;
    o.x = (va.x+vb.x)*g2 + bfc2; o.y = (va.y+vb.y)*g2 + bfc2;
    o.z = (va.z+vb.z)*g2 + bfc2; o.w = (va.w+vb.w)*g2 + bfc2;
    *(float4*)&d_out[(size_t)j*DD + e4] = o;
  }
}

// ---------------------------------------------------------------------------
// K4: ctx1 = (sum of v2 partials) * g1[row] + b_fc1  -> d_out
// ---------------------------------------------------------------------------
__global__ __launch_bounds__(256) void k_ctx1(
    const float* __restrict__ ws, const float* __restrict__ g1acc,
    const float* __restrict__ b_fc1p, float* __restrict__ d_out)
{
  const int i = blockIdx.x*256 + threadIdx.x;   // float4 index
  if (i >= 27*512) return;
  const int row = i >> 9, c4 = (i & 511)*4;
  const float* v2p = ws + V2P;
  const float* base = v2p + (size_t)row*DD + c4;
  float4 v0 = *(const float4*)(base);
  float4 v1 = *(const float4*)(base + SLS);
  float4 v2 = *(const float4*)(base + 2*SLS);
  float4 v3 = *(const float4*)(base + 3*SLS);
  const float g = g1acc[row], bb = b_fc1p[0];
  float4 o;
  o.x = ((v0.x+v1.x)+(v2.x+v3.x))*g + bb;
  o.y = ((v0.y+v1.y)+(v2.y+v3.y))*g + bb;
  o.z = ((v0.z+v1.z)+(v2.z+v3.z))*g + bb;
  o.w = ((v0.w+v1.w)+(v2.w+v3.w))*g + bb;
  *(float4*)&d_out[OFF_CTX1 + (size_t)row*DD + c4] = o;
}

// ---------------------------------------------------------------------------
extern "C" void kernel_launch(void* const* d_in, const int* in_sizes, int n_in,
                              void* d_out, int out_size, void* d_ws, size_t ws_size,
                              hipStream_t stream)
{
  const float* in1 = (const float*)d_in[0];
  const float* in2 = (const float*)d_in[1];
  P6 par;
  par.W[0] = (const float*)d_in[2];  par.b[0] = (const float*)d_in[3];   // Wq1
  par.W[1] = (const float*)d_in[4];  par.b[1] = (const float*)d_in[5];   // Wk1
  par.W[2] = (const float*)d_in[6];  par.b[2] = (const float*)d_in[7];   // Wv1
  par.W[3] = (const float*)d_in[8];  par.b[3] = (const float*)d_in[9];   // Wq2
  par.W[4] = (const float*)d_in[10]; par.b[4] = (const float*)d_in[11];  // Wk2
  par.W[5] = (const float*)d_in[12]; par.b[5] = (const float*)d_in[13];  // Wv2
  const float* wfc1 = (const float*)d_in[14]; const float* bfc1 = (const float*)d_in[15];
  const float* wfc2 = (const float*)d_in[16]; const float* bfc2 = (const float*)d_in[17];
  float* out = (float*)d_out;
  float* ws  = (float*)d_ws;
  float* g1acc = ws + G1A;

  hipMemsetAsync(g1acc, 0, 32*sizeof(float), stream);
  k6nt<<<1152, 256, 0, stream>>>(in1, in2, par, ws);
  kS<<<64, 256, 0, stream>>>(ws);
  k_finish<<<63, 256, 0, stream>>>(ws, wfc1, wfc2, bfc1, bfc2, g1acc, out);
  k_ctx1<<<54, 256, 0, stream>>>(ws, g1acc, bfc1, out);
}